// Round 9
// baseline (418.042 us; speedup 1.0000x reference)
//
#include <hip/hip_runtime.h>

#define NT 150      // trees
#define NPT 341     // nodes per tree
#define VOCAB 10000

typedef __attribute__((ext_vector_type(8))) short short8;
typedef __attribute__((ext_vector_type(4))) float floatx4;

__device__ __forceinline__ float sigf(float x){ return 1.0f/(1.0f+__expf(-x)); }
__device__ __forceinline__ float bf2f(ushort u){ union{unsigned i; float f;} v; v.i = ((unsigned)u)<<16; return v.f; }
__device__ __forceinline__ ushort f2bf(float x){ union{float f; unsigned i;} v; v.f = x; return (ushort)((v.i + 0x7fff + ((v.i>>16)&1))>>16); }

// ---- OCP e4m3fn encode (convE only, speed-irrelevant) ----------------------
__device__ unsigned char f2e4m3(float x){
  float a = fabsf(x);
  unsigned s = (x < 0.f) ? 1u : 0u;
  if (a != a) return (unsigned char)((s<<7)|0x7f);
  a = fminf(a, 448.f);
  unsigned E, M;
  if (a < 7.8125e-3f){
    M = (unsigned)rintf(a*512.f); E = 0;
    if (M > 7){ E = 1; M = 0; }
  } else {
    int e; float m = frexpf(a, &e);   // a = m*2^e, m in [0.5,1)
    if (e + 6 <= 0){
      M = (unsigned)rintf(a*512.f); E = 0;
      if (M > 7){ E = 1; M = 0; }
    } else {
      E = (unsigned)(e + 6);
      M = (unsigned)rintf((m*2.f - 1.f)*8.f);
      if (M > 7){ M = 0; E++; }
      if (E > 15){ E = 15; M = 6; }
    }
  }
  return (unsigned char)((s<<7)|(E<<3)|M);
}

// ---- OCP e4m3fn decode, branchless (~6 ops) --------------------------------
__device__ __forceinline__ float fp8d(unsigned b){
  unsigned e = (b>>3)&15u, m = b&7u, t = (e==0u) ? 1u : 0u;
  union{unsigned u; float f;} w;
  w.u = ((e + 120u + t)<<23) | (m<<20);
  float mag = w.f - (t ? 0.015625f : 0.f);
  return (b & 0x80u) ? -mag : mag;
}

// ---------- weights transpose+convert: fp32 [256][N] -> bf16 [N][256] -------
__global__ __launch_bounds__(256) void convW_k(
    const float* __restrict__ W1, const float* __restrict__ U1, const float* __restrict__ F1,
    const float* __restrict__ W2, const float* __restrict__ U2, const float* __restrict__ F2,
    ushort* Wt1, ushort* Ut1, ushort* Ft1, ushort* Wt2, ushort* Ut2, ushort* Ft2){
  __shared__ float T[32][33];
  const float* src; ushort* dst; int N;
  switch (blockIdx.z){
    case 0: src=W1; dst=Wt1; N=768; break;
    case 1: src=U1; dst=Ut1; N=768; break;
    case 2: src=F1; dst=Ft1; N=256; break;
    case 3: src=W2; dst=Wt2; N=768; break;
    case 4: src=U2; dst=Ut2; N=768; break;
    default: src=F2; dst=Ft2; N=256; break;
  }
  int n0 = blockIdx.x*32; if (n0 >= N) return;
  int k0 = blockIdx.y*32;
  int nl = threadIdx.x & 31, kb = threadIdx.x >> 5;
  #pragma unroll
  for (int i=0;i<4;i++){ int kk = kb*4+i; T[kk][nl] = src[(size_t)(k0+kk)*N + n0 + nl]; }
  __syncthreads();
  #pragma unroll
  for (int i=0;i<4;i++){ int nn = kb*4+i; dst[(size_t)(n0+nn)*256 + k0 + nl] = f2bf(T[nl][nn]); }
}

// ---------- embedding tables fp32 -> fp8 e4m3 (x64 scale) -------------------
__global__ __launch_bounds__(256) void convE_k(
    const float* __restrict__ e1, const float* __restrict__ e2,
    unsigned char* __restrict__ E1, unsigned char* __restrict__ E2){
  const float* s = blockIdx.y ? e2 : e1;
  unsigned char* d = blockIdx.y ? E2 : E1;
  size_t i = ((size_t)blockIdx.x*256 + threadIdx.x)*4;
  float4 v = *(const float4*)&s[i];
  uchar4 o;
  o.x = f2e4m3(v.x*64.f); o.y = f2e4m3(v.y*64.f);
  o.z = f2e4m3(v.z*64.f); o.w = f2e4m3(v.w*64.f);
  *(uchar4*)&d[i] = o;
}

// ---------- Kernel A: embed(fp8 gather) + leaf + l0, per 64-leaf subtree ----
// grid 1200 linear: br = bid&1 (XCD-parity -> one E table per XCD L2), s=bid>>1
__global__ __launch_bounds__(1024) void subtree_k(
    const int* __restrict__ f1, const int* __restrict__ f2,
    const unsigned char* __restrict__ E1, const unsigned char* __restrict__ E2,
    const ushort* __restrict__ Wt1, const float* __restrict__ b1,
    const ushort* __restrict__ Ut1, const ushort* __restrict__ Ft1, const float* __restrict__ Ufb1,
    const ushort* __restrict__ Wt2, const float* __restrict__ b2,
    const ushort* __restrict__ Ut2, const ushort* __restrict__ Ft2, const float* __restrict__ Ufb2,
    ushort* __restrict__ h1, ushort* __restrict__ c1,
    ushort* __restrict__ h2, ushort* __restrict__ c2,
    float* __restrict__ part){
  __shared__ __attribute__((aligned(16))) ushort As[8][64*40];
  __shared__ __attribute__((aligned(16))) ushort Ht[8][16*40];
  __shared__ float Csum[16][272];
  int bid = blockIdx.x;
  int br = bid & 1;
  int s = bid >> 1;                 // 0..599
  const int* feat = br ? f2 : f1;
  const unsigned char* E = br ? E2 : E1;
  const ushort* Wt = br ? Wt2 : Wt1;
  const float* biou = br ? b2 : b1;
  const ushort* Ut = br ? Ut2 : Ut1;
  const ushort* Ft = br ? Ft2 : Ft1;
  const float* Ufb = br ? Ufb2 : Ufb1;
  ushort* h = br ? h2 : h1;
  ushort* c = br ? c2 : c1;
  int tree = s >> 2, j = s & 3;
  size_t nbase = (size_t)tree*NPT;
  int tid = threadIdx.x, lane = tid & 63, wav = tid >> 6, quad = lane >> 4, l15 = lane & 15;

  { // --- embed: fp8 gather-mean straight into As ---
    int row = tid >> 4, seg = tid & 15;
    size_t node = nbase + 85 + 64*j + row;
    const int* f = feat + node*8;
    float sm[16];
    #pragma unroll
    for (int q=0;q<16;q++) sm[q]=0.f;
    #pragma unroll
    for (int t8=0;t8<8;t8++){
      uint4 rv = *(const uint4*)(E + (size_t)f[t8]*256 + seg*16);
      unsigned wd[4] = {rv.x, rv.y, rv.z, rv.w};
      #pragma unroll
      for (int w=0;w<4;w++)
        #pragma unroll
        for (int b8=0;b8<4;b8++)
          sm[w*4+b8] += fp8d((wd[w]>>(8*b8)) & 0xffu);
    }
    short8 o1, o2;
    #pragma unroll
    for (int q=0;q<8;q++){
      o1[q]=(short)f2bf(sm[q]*0.001953125f);      // 0.125 (mean) / 64 (scale)
      o2[q]=(short)f2bf(sm[8+q]*0.001953125f);
    }
    int cch = seg >> 1, off = (seg & 1)*16;
    *(short8*)&As[cch][row*40 + off]     = o1;
    *(short8*)&As[cch][row*40 + off + 8] = o2;
  }
  __syncthreads();

  int hcol = wav*16 + l15;
  int cch = hcol >> 5, coff = hcol & 31;
  float bi = biou[hcol], bo = biou[256+hcol], bu = biou[512+hcol];

  // --- leaf GEMM ---
  floatx4 acc[3][4];
  #pragma unroll
  for (int g=0;g<3;g++)
    #pragma unroll
    for (int r=0;r<4;r++) acc[g][r] = (floatx4){0.f,0.f,0.f,0.f};
  {
    const ushort* bp0 = Wt + (size_t)(0*256 + hcol)*256 + quad*8;
    const ushort* bp1 = Wt + (size_t)(1*256 + hcol)*256 + quad*8;
    const ushort* bp2 = Wt + (size_t)(2*256 + hcol)*256 + quad*8;
    #pragma unroll
    for (int k8=0;k8<8;k8++){
      short8 b0 = *(const short8*)(bp0 + k8*32);
      short8 b1 = *(const short8*)(bp1 + k8*32);
      short8 b2 = *(const short8*)(bp2 + k8*32);
      #pragma unroll
      for (int r=0;r<4;r++){
        short8 a = *(const short8*)&As[k8][(16*r + l15)*40 + quad*8];
        acc[0][r] = __builtin_amdgcn_mfma_f32_16x16x32_bf16(a, b0, acc[0][r], 0,0,0);
        acc[1][r] = __builtin_amdgcn_mfma_f32_16x16x32_bf16(a, b1, acc[1][r], 0,0,0);
        acc[2][r] = __builtin_amdgcn_mfma_f32_16x16x32_bf16(a, b2, acc[2][r], 0,0,0);
      }
    }
  }
  float hL[4][4], cL[4][4], htd[4];
  #pragma unroll
  for (int r=0;r<4;r++){
    htd[r] = 0.f;
    #pragma unroll
    for (int reg=0;reg<4;reg++){
      float iv = acc[0][r][reg] + bi;
      float ov = acc[1][r][reg] + bo;
      float uv = acc[2][r][reg] + bu;
      float cc_ = sigf(iv)*tanhf(uv);
      float hh = sigf(ov)*tanhf(cc_);
      cL[r][reg] = cc_; hL[r][reg] = hh; htd[r] += hh;
    }
  }
  __syncthreads();
  float sA = 0.f;
  #pragma unroll
  for (int r=0;r<4;r++){
    #pragma unroll
    for (int reg=0;reg<4;reg++){
      As[cch][(16*r + quad*4 + reg)*40 + coff] = f2bf(hL[r][reg]);
      sA += hL[r][reg];
    }
    Ht[cch][(4*r + quad)*40 + coff] = f2bf(htd[r]);
  }
  __syncthreads();

  // --- l0: forget per-child (A=leaf h) + iou via h_tild ---
  floatx4 af[4], ai, ao, au;
  #pragma unroll
  for (int r=0;r<4;r++) af[r] = (floatx4){0.f,0.f,0.f,0.f};
  ai = (floatx4){0.f,0.f,0.f,0.f}; ao = ai; au = ai;
  {
    const ushort* bfp = Ft + (size_t)hcol*256 + quad*8;
    const ushort* up0 = Ut + (size_t)(0*256 + hcol)*256 + quad*8;
    const ushort* up1 = Ut + (size_t)(256 + hcol)*256 + quad*8;
    const ushort* up2 = Ut + (size_t)(512 + hcol)*256 + quad*8;
    #pragma unroll
    for (int k8=0;k8<8;k8++){
      short8 Bf = *(const short8*)(bfp + k8*32);
      short8 B0 = *(const short8*)(up0 + k8*32);
      short8 B1 = *(const short8*)(up1 + k8*32);
      short8 B2 = *(const short8*)(up2 + k8*32);
      short8 ah = *(const short8*)&Ht[k8][l15*40 + quad*8];
      #pragma unroll
      for (int r=0;r<4;r++){
        short8 a = *(const short8*)&As[k8][(16*r + l15)*40 + quad*8];
        af[r] = __builtin_amdgcn_mfma_f32_16x16x32_bf16(a, Bf, af[r], 0,0,0);
      }
      ai = __builtin_amdgcn_mfma_f32_16x16x32_bf16(ah, B0, ai, 0,0,0);
      ao = __builtin_amdgcn_mfma_f32_16x16x32_bf16(ah, B1, ao, 0,0,0);
      au = __builtin_amdgcn_mfma_f32_16x16x32_bf16(ah, B2, au, 0,0,0);
    }
  }
  float ufb = Ufb[hcol];
  #pragma unroll
  for (int r=0;r<4;r++){
    float cs = 0.f;
    #pragma unroll
    for (int reg=0;reg<4;reg++) cs += sigf(af[r][reg] + ufb) * cL[r][reg];
    Csum[4*r + quad][hcol] = cs;
  }
  #pragma unroll
  for (int reg=0;reg<4;reg++){
    int p = quad*4 + reg;
    float cs = Csum[p][hcol];
    float iv = ai[reg] + bi, ov = ao[reg] + bo, uv = au[reg] + bu;
    float cn = sigf(iv)*tanhf(uv) + cs;
    float hn = sigf(ov)*tanhf(cn);
    sA += hn;
    size_t off = (nbase + 21 + 16*j + p)*256 + hcol;
    h[off] = f2bf(hn);
    c[off] = f2bf(cn);
  }
  sA += __shfl_xor(sA, 16);
  sA += __shfl_xor(sA, 32);
  if (quad == 0) part[((size_t)(s*2 + br))*256 + hcol] = sA;
}

// ---------- Kernel B: l1 + l2 + root + readout, per (tree,branch) -----------
// grid 300 linear: br = bid&1 (XCD-parity matches subtree_k weight residency)
__global__ __launch_bounds__(1024) void upper_k(
    const ushort* __restrict__ Ut1, const ushort* __restrict__ Ft1,
    const float* __restrict__ Ufb1, const float* __restrict__ b1,
    const ushort* __restrict__ Ut2, const ushort* __restrict__ Ft2,
    const float* __restrict__ Ufb2, const float* __restrict__ b2,
    const ushort* __restrict__ h1, const ushort* __restrict__ c1,
    const ushort* __restrict__ h2, const ushort* __restrict__ c2,
    const float* __restrict__ part,
    float* __restrict__ m1, float* __restrict__ m2){
  __shared__ __attribute__((aligned(16))) ushort As[8][64*40];
  __shared__ __attribute__((aligned(16))) ushort Ht[8][16*40];
  __shared__ float Csum[16][272];
  int bid = blockIdx.x;
  int br = bid & 1;
  int tree = bid >> 1;
  const ushort* Ut = br ? Ut2 : Ut1;
  const ushort* Ft = br ? Ft2 : Ft1;
  const float* Ufb = br ? Ufb2 : Ufb1;
  const float* biou = br ? b2 : b1;
  const ushort* h = br ? h2 : h1;
  const ushort* c = br ? c2 : c1;
  float* mo = br ? m2 : m1;
  size_t nbase = (size_t)tree*NPT;
  int tid = threadIdx.x, lane = tid & 63, wav = tid >> 6, quad = lane >> 4, l15 = lane & 15;
  int hcol = wav*16 + l15;
  int cch = hcol >> 5, coff = hcol & 31;
  float bi = biou[hcol], bo = biou[256+hcol], bu = biou[512+hcol];
  float ufb = Ufb[hcol];

  { // stage l0 h (64 nodes, local 21..84)
    int row = tid >> 4, seg = tid & 15;
    const ushort* src = h + (nbase + 21 + row)*256 + seg*16;
    short8 a = *(const short8*)src;
    short8 b = *(const short8*)(src+8);
    int cc2 = seg >> 1, off = (seg & 1)*16;
    *(short8*)&As[cc2][row*40 + off]     = a;
    *(short8*)&As[cc2][row*40 + off + 8] = b;
  }
  float cL0[4][4];
  #pragma unroll
  for (int r=0;r<4;r++)
    #pragma unroll
    for (int reg=0;reg<4;reg++)
      cL0[r][reg] = bf2f(c[(nbase + 21 + 16*r + quad*4 + reg)*256 + hcol]);
  __syncthreads();
  if (tid < 512){ // h_tild (16 x 256)
    int n = tid >> 5, sg = tid & 31;
    int cc2 = sg >> 2, off = (sg & 3)*8;
    float s8[8];
    #pragma unroll
    for (int q=0;q<8;q++) s8[q]=0.f;
    #pragma unroll
    for (int i=0;i<4;i++){
      short8 v = *(const short8*)&As[cc2][(4*n+i)*40 + off];
      #pragma unroll
      for (int q=0;q<8;q++) s8[q] += bf2f((ushort)v[q]);
    }
    short8 o;
    #pragma unroll
    for (int q=0;q<8;q++) o[q] = (short)f2bf(s8[q]);
    *(short8*)&Ht[cc2][n*40 + off] = o;
  }
  __syncthreads();

  const ushort* bfp = Ft + (size_t)hcol*256 + quad*8;
  const ushort* up0 = Ut + (size_t)(0*256 + hcol)*256 + quad*8;
  const ushort* up1 = Ut + (size_t)(256 + hcol)*256 + quad*8;
  const ushort* up2 = Ut + (size_t)(512 + hcol)*256 + quad*8;

  // --- l1 ---
  floatx4 af1[4], ai1, ao1, au1;
  #pragma unroll
  for (int r=0;r<4;r++) af1[r] = (floatx4){0.f,0.f,0.f,0.f};
  ai1 = (floatx4){0.f,0.f,0.f,0.f}; ao1 = ai1; au1 = ai1;
  #pragma unroll
  for (int k8=0;k8<8;k8++){
    short8 Bf = *(const short8*)(bfp + k8*32);
    short8 B0 = *(const short8*)(up0 + k8*32);
    short8 B1 = *(const short8*)(up1 + k8*32);
    short8 B2 = *(const short8*)(up2 + k8*32);
    short8 ah = *(const short8*)&Ht[k8][l15*40 + quad*8];
    #pragma unroll
    for (int r=0;r<4;r++){
      short8 a = *(const short8*)&As[k8][(16*r + l15)*40 + quad*8];
      af1[r] = __builtin_amdgcn_mfma_f32_16x16x32_bf16(a, Bf, af1[r], 0,0,0);
    }
    ai1 = __builtin_amdgcn_mfma_f32_16x16x32_bf16(ah, B0, ai1, 0,0,0);
    ao1 = __builtin_amdgcn_mfma_f32_16x16x32_bf16(ah, B1, ao1, 0,0,0);
    au1 = __builtin_amdgcn_mfma_f32_16x16x32_bf16(ah, B2, au1, 0,0,0);
  }
  #pragma unroll
  for (int r=0;r<4;r++){
    float cs = 0.f;
    #pragma unroll
    for (int reg=0;reg<4;reg++) cs += sigf(af1[r][reg] + ufb) * cL0[r][reg];
    Csum[4*r + quad][hcol] = cs;
  }
  float h1v[4], c1v[4], sB = 0.f;
  #pragma unroll
  for (int reg=0;reg<4;reg++){
    int p = quad*4 + reg;
    float cs = Csum[p][hcol];
    float iv = ai1[reg]+bi, ov = ao1[reg]+bo, uv = au1[reg]+bu;
    c1v[reg] = sigf(iv)*tanhf(uv) + cs;
    h1v[reg] = sigf(ov)*tanhf(c1v[reg]);
    sB += h1v[reg];
  }
  __syncthreads();
  #pragma unroll
  for (int reg=0;reg<4;reg++)
    Ht[cch][(quad*4 + reg)*40 + coff] = f2bf(h1v[reg]);
  __syncthreads();

  // --- l2 ---
  floatx4 af2, ai2, ao2, au2;
  af2 = (floatx4){0.f,0.f,0.f,0.f}; ai2 = af2; ao2 = af2; au2 = af2;
  #pragma unroll
  for (int k8=0;k8<8;k8++){
    short8 Bf = *(const short8*)(bfp + k8*32);
    short8 B0 = *(const short8*)(up0 + k8*32);
    short8 B1 = *(const short8*)(up1 + k8*32);
    short8 B2 = *(const short8*)(up2 + k8*32);
    short8 a = *(const short8*)&Ht[k8][l15*40 + quad*8];
    af2 = __builtin_amdgcn_mfma_f32_16x16x32_bf16(a, Bf, af2, 0,0,0);
    ai2 = __builtin_amdgcn_mfma_f32_16x16x32_bf16(a, B0, ai2, 0,0,0);
    ao2 = __builtin_amdgcn_mfma_f32_16x16x32_bf16(a, B1, ao2, 0,0,0);
    au2 = __builtin_amdgcn_mfma_f32_16x16x32_bf16(a, B2, au2, 0,0,0);
  }
  float cs2 = 0.f;
  #pragma unroll
  for (int reg=0;reg<4;reg++) cs2 += sigf(af2[reg] + ufb) * c1v[reg];
  float iv2 = ai2[0]+ai2[1]+ai2[2]+ai2[3] + bi;
  float ov2 = ao2[0]+ao2[1]+ao2[2]+ao2[3] + bo;
  float uv2 = au2[0]+au2[1]+au2[2]+au2[3] + bu;
  float c2v = sigf(iv2)*tanhf(uv2) + cs2;
  float h2v = sigf(ov2)*tanhf(c2v);
  sB += h2v;
  __syncthreads();
  Ht[cch][quad*40 + coff] = f2bf(h2v);
  #pragma unroll
  for (int z=1;z<4;z++) Ht[cch][(quad + 4*z)*40 + coff] = 0;
  __syncthreads();

  // --- root ---
  floatx4 af3, ai3, ao3, au3;
  af3 = (floatx4){0.f,0.f,0.f,0.f}; ai3 = af3; ao3 = af3; au3 = af3;
  #pragma unroll
  for (int k8=0;k8<8;k8++){
    short8 Bf = *(const short8*)(bfp + k8*32);
    short8 B0 = *(const short8*)(up0 + k8*32);
    short8 B1 = *(const short8*)(up1 + k8*32);
    short8 B2 = *(const short8*)(up2 + k8*32);
    short8 a = *(const short8*)&Ht[k8][l15*40 + quad*8];
    af3 = __builtin_amdgcn_mfma_f32_16x16x32_bf16(a, Bf, af3, 0,0,0);
    ai3 = __builtin_amdgcn_mfma_f32_16x16x32_bf16(a, B0, ai3, 0,0,0);
    ao3 = __builtin_amdgcn_mfma_f32_16x16x32_bf16(a, B1, ao3, 0,0,0);
    au3 = __builtin_amdgcn_mfma_f32_16x16x32_bf16(a, B2, au3, 0,0,0);
  }
  float c2c[4];
  #pragma unroll
  for (int reg=0;reg<4;reg++) c2c[reg] = __shfl(c2v, reg*16 + l15);
  {
    float cs3 = 0.f;
    #pragma unroll
    for (int reg=0;reg<4;reg++) cs3 += sigf(af3[reg] + ufb) * c2c[reg];
    float iv3 = ai3[0]+ai3[1]+ai3[2]+ai3[3] + bi;
    float ov3 = ao3[0]+ao3[1]+ao3[2]+ao3[3] + bo;
    float uv3 = au3[0]+au3[1]+au3[2]+au3[3] + bu;
    float c3 = sigf(iv3)*tanhf(uv3) + cs3;
    float hr = sigf(ov3)*tanhf(c3);
    if (quad == 0) sB += hr;
  }
  sB += __shfl_xor(sB, 16);
  sB += __shfl_xor(sB, 32);
  if (quad == 0){
    float tot = sB;
    #pragma unroll
    for (int jj=0;jj<4;jj++)
      tot += part[((size_t)((tree*4 + jj)*2 + br))*256 + hcol];
    mo[tree*256 + hcol] = fmaxf(tot*(1.0f/341.0f), 0.f);
  }
}

// ---------- final: concat @ Wf -> leaky_relu -> softmax ---------------------
__global__ __launch_bounds__(64) void final_k(const float* __restrict__ m1,
    const float* __restrict__ m2, const float* __restrict__ Wf,
    const float* __restrict__ bf, float* __restrict__ out){
  int tree = blockIdx.x; int t = threadIdx.x;
  float p0=0.f, p1=0.f;
  for (int k=t;k<512;k+=64){
    float x = (k<256) ? m1[tree*256+k] : m2[tree*256+(k-256)];
    p0 += x*Wf[k*2+0]; p1 += x*Wf[k*2+1];
  }
  #pragma unroll
  for (int off=32; off>0; off>>=1){
    p0 += __shfl_down(p0, off);
    p1 += __shfl_down(p1, off);
  }
  if (t==0){
    float l0 = p0+bf[0], l1 = p1+bf[1];
    l0 = (l0>0.f)?l0:0.01f*l0;
    l1 = (l1>0.f)?l1:0.01f*l1;
    float mx = fmaxf(l0,l1);
    float e0 = __expf(l0-mx), e1 = __expf(l1-mx);
    float inv = 1.0f/(e0+e1);
    out[tree*2+0] = e0*inv; out[tree*2+1] = e1*inv;
  }
}

extern "C" void kernel_launch(void* const* d_in, const int* in_sizes, int n_in,
                              void* d_out, int out_size, void* d_ws, size_t ws_size,
                              hipStream_t stream) {
  const int*   feat1 = (const int*)  d_in[0];
  const int*   feat2 = (const int*)  d_in[1];
  const float* emb1  = (const float*)d_in[2];
  const float* emb2  = (const float*)d_in[3];
  const float* Wiou1 = (const float*)d_in[4];
  const float* Wiou2 = (const float*)d_in[5];
  const float* Uiou1 = (const float*)d_in[6];
  const float* Uiou2 = (const float*)d_in[7];
  const float* UfW1  = (const float*)d_in[8];
  const float* Ufb1  = (const float*)d_in[9];
  const float* UfW2  = (const float*)d_in[10];
  const float* Ufb2  = (const float*)d_in[11];
  const float* biou1 = (const float*)d_in[12];
  const float* biou2 = (const float*)d_in[13];
  const float* Wf    = (const float*)d_in[14];
  const float* bfv   = (const float*)d_in[15];
  float* out = (float*)d_out;

  char* ws = (char*)d_ws;
  ushort* h1  = (ushort*)ws;  ws += (size_t)NT*NPT*256*2;
  ushort* h2  = (ushort*)ws;  ws += (size_t)NT*NPT*256*2;
  ushort* c1  = (ushort*)ws;  ws += (size_t)NT*NPT*256*2;
  ushort* c2  = (ushort*)ws;  ws += (size_t)NT*NPT*256*2;
  unsigned char* E1 = (unsigned char*)ws;  ws += (size_t)VOCAB*256;
  unsigned char* E2 = (unsigned char*)ws;  ws += (size_t)VOCAB*256;
  ushort* Wt1 = (ushort*)ws;  ws += 768*256*2;
  ushort* Ut1 = (ushort*)ws;  ws += 768*256*2;
  ushort* Ft1 = (ushort*)ws;  ws += 256*256*2;
  ushort* Wt2 = (ushort*)ws;  ws += 768*256*2;
  ushort* Ut2 = (ushort*)ws;  ws += 768*256*2;
  ushort* Ft2 = (ushort*)ws;  ws += 256*256*2;
  float*  part = (float*)ws;  ws += (size_t)600*2*256*4;
  float*  m1  = (float*)ws;   ws += (size_t)NT*256*4;
  float*  m2  = (float*)ws;   ws += (size_t)NT*256*4;

  convE_k<<<dim3(2500, 2), 256, 0, stream>>>(emb1, emb2, E1, E2);
  convW_k<<<dim3(24, 8, 6), 256, 0, stream>>>(Wiou1, Uiou1, UfW1, Wiou2, Uiou2, UfW2,
                                              Wt1, Ut1, Ft1, Wt2, Ut2, Ft2);
  subtree_k<<<1200, 1024, 0, stream>>>(feat1, feat2, E1, E2,
                                       Wt1, biou1, Ut1, Ft1, Ufb1,
                                       Wt2, biou2, Ut2, Ft2, Ufb2,
                                       h1, c1, h2, c2, part);
  upper_k<<<300, 1024, 0, stream>>>(Ut1, Ft1, Ufb1, biou1,
                                    Ut2, Ft2, Ufb2, biou2,
                                    h1, c1, h2, c2, part, m1, m2);
  final_k<<<NT, 64, 0, stream>>>(m1, m2, Wf, bfv, out);
}